// Round 4
// baseline (342.652 us; speedup 1.0000x reference)
//
#include <hip/hip_runtime.h>
#include <cstdint>
#include <cstddef>

typedef __bf16 bf16;
typedef float f32x4 __attribute__((ext_vector_type(4)));
typedef __bf16 bf16x8 __attribute__((ext_vector_type(8)));
typedef __bf16 bf16x4 __attribute__((ext_vector_type(4)));

#define MFMA16(a, b, c) __builtin_amdgcn_mfma_f32_16x16x32_bf16((a), (b), (c), 0, 0, 0)

__device__ __forceinline__ void gload_lds16(const void* g, void* l) {
  __builtin_amdgcn_global_load_lds((__attribute__((address_space(1))) void*)g,
                                   (__attribute__((address_space(3))) void*)l,
                                   16, 0, 0);
}

// ---------------------------------------------------------------------------
// All four weight transposes in one launch (flat grid).
// m2 (wi) writes INTERLEAVED rows: n' = 2n (n<1152, x-col) / 2(n-1152)+1 (gate).
// ---------------------------------------------------------------------------
__global__ __launch_bounds__(256) void wconv_all(const float* __restrict__ wqkv,
                                                 const float* __restrict__ woa,
                                                 const float* __restrict__ wi,
                                                 const float* __restrict__ wom,
                                                 bf16* __restrict__ wqkvT,
                                                 bf16* __restrict__ woaT,
                                                 bf16* __restrict__ wiIT,
                                                 bf16* __restrict__ womT) {
  int id = blockIdx.x;
  const float* W;
  bf16* Wt;
  int K, N, bx, by;
  bool inter = false;
  if (id < 1728) { W = wqkv; Wt = wqkvT; K = 768; N = 2304; bx = id % 72; by = id / 72; }
  else if (id < 2304) { id -= 1728; W = woa; Wt = woaT; K = 768; N = 768; bx = id % 24; by = id / 24; }
  else if (id < 4032) { id -= 2304; W = wi; Wt = wiIT; K = 768; N = 2304; inter = true; bx = id % 72; by = id / 72; }
  else { id -= 4032; W = wom; Wt = womT; K = 1152; N = 768; bx = id % 24; by = id / 24; }

  __shared__ float tile[32][33];
  const int n0 = bx * 32, k0 = by * 32;
  const int t = threadIdx.x;
  const int c = t & 31, r = t >> 5;
#pragma unroll
  for (int i = 0; i < 4; ++i)
    tile[r + i * 8][c] = W[(size_t)(k0 + r + i * 8) * N + n0 + c];
  __syncthreads();
#pragma unroll
  for (int i = 0; i < 4; ++i) {
    int n = n0 + r + i * 8;
    int nw = inter ? ((n < 1152) ? 2 * n : 2 * (n - 1152) + 1) : n;
    Wt[(size_t)nw * K + k0 + c] = (bf16)tile[c][r + i * 8];
  }
}

// ---------------------------------------------------------------------------
// LayerNorm (center=False): subtract mean, no beta -> bf16
// ---------------------------------------------------------------------------
__global__ __launch_bounds__(256) void ln_kernel(const float* __restrict__ X,
                                                 const float* __restrict__ gamma,
                                                 bf16* __restrict__ out) {
  const int row = blockIdx.x, t = threadIdx.x;
  const float* xr = X + (size_t)row * 768;
  float v0 = xr[t], v1 = xr[t + 256], v2 = xr[t + 512];
  float s = v0 + v1 + v2;
  float s2 = v0 * v0 + v1 * v1 + v2 * v2;
#pragma unroll
  for (int m = 1; m <= 32; m <<= 1) {
    s += __shfl_xor(s, m, 64);
    s2 += __shfl_xor(s2, m, 64);
  }
  __shared__ float red[8];
  const int w = t >> 6, lane = t & 63;
  if (lane == 0) { red[w] = s; red[4 + w] = s2; }
  __syncthreads();
  s = red[0] + red[1] + red[2] + red[3];
  s2 = red[4] + red[5] + red[6] + red[7];
  const float mu = s * (1.f / 768.f);
  const float var = s2 * (1.f / 768.f) - mu * mu;
  const float rs = rsqrtf(var + 1e-5f);
  out[(size_t)row * 768 + t] = (bf16)((v0 - mu) * rs * gamma[t]);
  out[(size_t)row * 768 + t + 256] = (bf16)((v1 - mu) * rs * gamma[t + 256]);
  out[(size_t)row * 768 + t + 512] = (bf16)((v2 - mu) * rs * gamma[t + 512]);
}

// ---------------------------------------------------------------------------
// Generic NT GEMM: C[M][N] = A * Bt^T (+ f32 residual), TOUT out.
// ---------------------------------------------------------------------------
template <int BM, bool RES, typename TOUT>
__global__ __launch_bounds__(256) void gemm_bt(const bf16* __restrict__ A,
                                               const bf16* __restrict__ Bt,
                                               const float* __restrict__ Res,
                                               TOUT* __restrict__ C, int M, int N, int K) {
  constexpr int MT = BM / 32;
  __shared__ __align__(16) bf16 As[BM * 64];
  __shared__ __align__(16) bf16 Bs[128 * 64];
  const int t = threadIdx.x;
  const int lane = t & 63;
  const int w = t >> 6;
  const int wm = w >> 1, wn = w & 1;
  const int row0 = blockIdx.y * BM, col0 = blockIdx.x * 128;
  const int rm = lane & 15, qd = lane >> 4;
  f32x4 acc[MT][4] = {};
  for (int k0 = 0; k0 < K; k0 += 64) {
#pragma unroll
    for (int i = 0; i < BM / 32; ++i) {
      int c = i * 256 + t;
      int r = c >> 3, j = (c & 7) ^ (r & 7);
      gload_lds16(A + (size_t)(row0 + r) * K + (k0 + j * 8), &As[c * 8]);
    }
#pragma unroll
    for (int i = 0; i < 4; ++i) {
      int c = i * 256 + t;
      int r = c >> 3, j = (c & 7) ^ (r & 7);
      gload_lds16(Bt + (size_t)(col0 + r) * K + (k0 + j * 8), &Bs[c * 8]);
    }
    __syncthreads();
#pragma unroll
    for (int kb = 0; kb < 2; ++kb) {
      bf16x8 af[MT], bfr[4];
#pragma unroll
      for (int mt = 0; mt < MT; ++mt) {
        int r = wm * (MT * 16) + mt * 16 + rm;
        af[mt] = *(const bf16x8*)&As[r * 64 + (((kb * 4 + qd) ^ (r & 7)) * 8)];
      }
#pragma unroll
      for (int nt = 0; nt < 4; ++nt) {
        int r = wn * 64 + nt * 16 + rm;
        bfr[nt] = *(const bf16x8*)&Bs[r * 64 + (((kb * 4 + qd) ^ (r & 7)) * 8)];
      }
#pragma unroll
      for (int mt = 0; mt < MT; ++mt)
#pragma unroll
        for (int nt = 0; nt < 4; ++nt)
          acc[mt][nt] = MFMA16(af[mt], bfr[nt], acc[mt][nt]);
    }
    __syncthreads();
  }
#pragma unroll
  for (int mt = 0; mt < MT; ++mt)
#pragma unroll
    for (int nt = 0; nt < 4; ++nt) {
      const int gc = col0 + wn * 64 + nt * 16 + rm;
#pragma unroll
      for (int r = 0; r < 4; ++r) {
        const int gr = row0 + wm * (MT * 16) + mt * 16 + qd * 4 + r;
        float v = acc[mt][nt][r];
        const size_t idx = (size_t)gr * N + gc;
        if (RES) v += Res[idx];
        C[idx] = (TOUT)v;
      }
    }
}

// ---------------------------------------------------------------------------
// Wi GEMM over INTERLEAVED wiIT (2304 rows: even=x, odd=gate).
// Stock gemm_bt<128> K-loop; epilogue pairs x/gate via shfl_xor(1).
// out mlp [8192][1152] = gelu(x)*gate.
// ---------------------------------------------------------------------------
__global__ __launch_bounds__(256) void gemm_wi(const bf16* __restrict__ A,
                                               const bf16* __restrict__ Bt,
                                               bf16* __restrict__ outp) {
  __shared__ __align__(16) bf16 As[128 * 64];
  __shared__ __align__(16) bf16 Bs[128 * 64];
  const int t = threadIdx.x;
  const int lane = t & 63;
  const int w = t >> 6;
  const int wm = w >> 1, wn = w & 1;
  const int row0 = blockIdx.y * 128, col0 = blockIdx.x * 128;
  const int rm = lane & 15, qd = lane >> 4;
  f32x4 acc[4][4] = {};
  for (int k0 = 0; k0 < 768; k0 += 64) {
#pragma unroll
    for (int i = 0; i < 4; ++i) {
      int c = i * 256 + t;
      int r = c >> 3, j = (c & 7) ^ (r & 7);
      gload_lds16(A + (size_t)(row0 + r) * 768 + (k0 + j * 8), &As[c * 8]);
      gload_lds16(Bt + (size_t)(col0 + r) * 768 + (k0 + j * 8), &Bs[c * 8]);
    }
    __syncthreads();
#pragma unroll
    for (int kb = 0; kb < 2; ++kb) {
      bf16x8 af[4], bfr[4];
#pragma unroll
      for (int mt = 0; mt < 4; ++mt) {
        int r = wm * 64 + mt * 16 + rm;
        af[mt] = *(const bf16x8*)&As[r * 64 + (((kb * 4 + qd) ^ (r & 7)) * 8)];
      }
#pragma unroll
      for (int nt = 0; nt < 4; ++nt) {
        int r = wn * 64 + nt * 16 + rm;
        bfr[nt] = *(const bf16x8*)&Bs[r * 64 + (((kb * 4 + qd) ^ (r & 7)) * 8)];
      }
#pragma unroll
      for (int mt = 0; mt < 4; ++mt)
#pragma unroll
        for (int nt = 0; nt < 4; ++nt)
          acc[mt][nt] = MFMA16(af[mt], bfr[nt], acc[mt][nt]);
    }
    __syncthreads();
  }
#pragma unroll
  for (int mt = 0; mt < 4; ++mt)
#pragma unroll
    for (int nt = 0; nt < 4; ++nt) {
      const int ci = col0 + wn * 64 + nt * 16 + rm;  // interleaved col; even<->rm even
#pragma unroll
      for (int r = 0; r < 4; ++r) {
        const int gr = row0 + wm * 64 + mt * 16 + qd * 4 + r;
        float v = acc[mt][nt][r];
        float other = __shfl_xor(v, 1, 64);
        if ((rm & 1) == 0) {
          float x = v, g = other;
          float ge = 0.5f * x * (1.0f + erff(x * 0.70710678118654752f));
          outp[(size_t)gr * 1152 + (ci >> 1)] = (bf16)(ge * g);
        }
      }
    }
}

// ---------------------------------------------------------------------------
// QKV GEMM with fused RoPE + head-split + V-transpose epilogue.
// Blocks are type-homogeneous: bx 0-5 -> Q heads, 6-11 -> K heads, 12-17 -> V.
// V-blocks transpose through LDS scratch (aliases As/Bs) for 256B-coalesced
// stores to Vt[bh*64+d][s].
// ---------------------------------------------------------------------------
__global__ __launch_bounds__(256) void gemm_qkv(const bf16* __restrict__ A,
                                                const bf16* __restrict__ Bt,
                                                bf16* __restrict__ Qb,
                                                bf16* __restrict__ Kb,
                                                bf16* __restrict__ Vt) {
  __shared__ __align__(16) bf16 SM[17408];  // As[8192] | Bs[8192]; scratch[128*136]
  bf16* As = SM;
  bf16* Bs = SM + 8192;

  const int t = threadIdx.x;
  const int lane = t & 63;
  const int w = t >> 6;
  const int wm = w >> 1, wn = w & 1;
  const int row0 = blockIdx.y * 128, col0 = blockIdx.x * 128;
  const int rm = lane & 15, qd = lane >> 4;
  f32x4 acc[4][4] = {};
  for (int k0 = 0; k0 < 768; k0 += 64) {
#pragma unroll
    for (int i = 0; i < 4; ++i) {
      int c = i * 256 + t;
      int r = c >> 3, j = (c & 7) ^ (r & 7);
      gload_lds16(A + (size_t)(row0 + r) * 768 + (k0 + j * 8), &As[c * 8]);
      gload_lds16(Bt + (size_t)(col0 + r) * 768 + (k0 + j * 8), &Bs[c * 8]);
    }
    __syncthreads();
#pragma unroll
    for (int kb = 0; kb < 2; ++kb) {
      bf16x8 af[4], bfr[4];
#pragma unroll
      for (int mt = 0; mt < 4; ++mt) {
        int r = wm * 64 + mt * 16 + rm;
        af[mt] = *(const bf16x8*)&As[r * 64 + (((kb * 4 + qd) ^ (r & 7)) * 8)];
      }
#pragma unroll
      for (int nt = 0; nt < 4; ++nt) {
        int r = wn * 64 + nt * 16 + rm;
        bfr[nt] = *(const bf16x8*)&Bs[r * 64 + (((kb * 4 + qd) ^ (r & 7)) * 8)];
      }
#pragma unroll
      for (int mt = 0; mt < 4; ++mt)
#pragma unroll
        for (int nt = 0; nt < 4; ++nt)
          acc[mt][nt] = MFMA16(af[mt], bfr[nt], acc[mt][nt]);
    }
    __syncthreads();
  }

  // ---- fused epilogue
  const int head_id = blockIdx.x * 2 + wn;  // 0..35
  const int typ = blockIdx.x / 6;           // block-uniform: 0=q 1=k 2=v
  const int b = row0 >> 11;
  const int sblk = row0 & 2047;
  const int sw = sblk + wm * 64;            // wave s-base

  if (typ < 2) {
    const int h = head_id - typ * 12;
    const size_t bhbase = (size_t)(b * 12 + h) * 2048;
    bf16* dst = typ ? Kb : Qb;
    float invf[2];
#pragma unroll
    for (int nt = 0; nt < 2; ++nt)
      invf[nt] = exp2f((float)(nt * 16 + rm) * -0.41524101186092029f);  // 10000^(-d/32)
#pragma unroll
    for (int mt = 0; mt < 4; ++mt)
#pragma unroll
      for (int r = 0; r < 4; ++r) {
        int s = sw + mt * 16 + qd * 4 + r;
#pragma unroll
        for (int nt = 0; nt < 2; ++nt) {
          float ang = (float)s * invf[nt];
          float rev = ang * 0.15915494309189535f;
          rev -= floorf(rev);
          float sn = __builtin_amdgcn_sinf(rev);
          float cs = __builtin_amdgcn_cosf(rev);
          float x1 = acc[mt][nt][r], x2 = acc[mt][nt + 2][r];
          int d = nt * 16 + rm;
          dst[(bhbase + s) * 64 + d] = (bf16)(x1 * cs - x2 * sn);
          dst[(bhbase + s) * 64 + d + 32] = (bf16)(x2 * cs + x1 * sn);
        }
      }
  } else {
    // write acc to scratch [hd][s], hd = wn*64 + d (128 rows, stride 136)
#pragma unroll
    for (int mt = 0; mt < 4; ++mt)
#pragma unroll
      for (int nt = 0; nt < 4; ++nt) {
        int hd = wn * 64 + nt * 16 + rm;
        int sl = wm * 64 + mt * 16 + qd * 4;  // 4 consecutive s
        bf16x4 v4;
#pragma unroll
        for (int r = 0; r < 4; ++r) v4[r] = (bf16)acc[mt][nt][r];
        *(bf16x4*)&SM[hd * 136 + sl] = v4;
      }
    __syncthreads();
    // coalesced read+store: 8 iters x 256 threads x 16B covers 128hd x 128s
    const int h0 = blockIdx.x * 2 - 24;  // first v-head of this block
#pragma unroll
    for (int it = 0; it < 8; ++it) {
      int cc = it * 256 + t;
      int hd = cc >> 4, s8 = (cc & 15) * 8;
      bf16x8 vv = *(const bf16x8*)&SM[hd * 136 + s8];
      size_t grow = (size_t)(b * 12 + h0 + (hd >> 6)) * 64 + (hd & 63);
      *(bf16x8*)&Vt[grow * 2048 + sblk + s8] = vv;
    }
  }
}

// ---------------------------------------------------------------------------
// Sliding-window attention (unchanged).
// ---------------------------------------------------------------------------
__global__ __launch_bounds__(256) void attn_kernel(const bf16* __restrict__ Qb,
                                                   const bf16* __restrict__ Kb,
                                                   const bf16* __restrict__ Vt,
                                                   const float* __restrict__ am,
                                                   bf16* __restrict__ ctx) {
  __shared__ __align__(16) bf16 KP[64 * 200];
  __shared__ __align__(16) bf16 Vts[64 * 192];
  bf16* Ks = KP;
  bf16* Ps = KP;

  const int t = threadIdx.x;
  const int lane = t & 63, w = t >> 6;
  const int rm = lane & 15, qd = lane >> 4;
  const int s0 = blockIdx.x * 64;
  const int bh = blockIdx.y;
  const int b = bh / 12, h = bh - b * 12;
  const size_t baseQ = (size_t)bh * 2048;

#pragma unroll
  for (int i = 0; i < 6; ++i) {
    int c = i * 256 + t;
    int r = c >> 3, j = (c & 7) ^ (r & 7);
    int key = min(max(s0 - 64 + r, 0), 2047);
    gload_lds16(Kb + (baseQ + key) * 64 + j * 8, &Ks[c * 8]);
  }
#pragma unroll
  for (int i = 0; i < 6; ++i) {
    int c = i * 256 + t;
    int r = c / 24, jl = c - r * 24;
    int j = (jl & 24) | ((jl & 7) ^ (r & 7));
    int k0 = min(max(s0 - 64 + j * 8, 0), 2040);
    gload_lds16(Vt + ((size_t)bh * 64 + r) * 2048 + k0, &Vts[c * 8]);
  }

  bf16x8 aq[2];
#pragma unroll
  for (int kb = 0; kb < 2; ++kb)
    aq[kb] = *(const bf16x8*)&Qb[(baseQ + s0 + w * 16 + rm) * 64 + kb * 32 + qd * 8];

  float msk[12][4];
#pragma unroll
  for (int nt = 0; nt < 12; ++nt) {
    int key = s0 - 64 + nt * 16 + rm;
#pragma unroll
    for (int r = 0; r < 4; ++r) {
      int qpos = s0 + w * 16 + qd * 4 + r;
      bool valid = (key >= 0) && (key < 2048) && (key - qpos <= 64) && (qpos - key <= 64);
      msk[nt][r] = valid ? am[((size_t)b * 2048 + qpos) * 2048 + key] : -3e38f;
    }
  }
  __syncthreads();

  f32x4 sc[12];
#pragma unroll
  for (int nt = 0; nt < 12; ++nt) {
    f32x4 a = {0.f, 0.f, 0.f, 0.f};
#pragma unroll
    for (int kb = 0; kb < 2; ++kb) {
      int r = nt * 16 + rm;
      bf16x8 bk = *(const bf16x8*)&Ks[r * 64 + (((kb * 4 + qd) ^ (rm & 7)) * 8)];
      a = MFMA16(aq[kb], bk, a);
    }
    sc[nt] = a;
  }

  float mx[4] = {-3e38f, -3e38f, -3e38f, -3e38f};
#pragma unroll
  for (int nt = 0; nt < 12; ++nt)
#pragma unroll
    for (int r = 0; r < 4; ++r) {
      float v = (msk[nt][r] <= -2.9e38f) ? -3e38f : sc[nt][r] * 0.125f + msk[nt][r];
      sc[nt][r] = v;
      mx[r] = fmaxf(mx[r], v);
    }
#pragma unroll
  for (int r = 0; r < 4; ++r)
#pragma unroll
    for (int m = 1; m <= 8; m <<= 1) mx[r] = fmaxf(mx[r], __shfl_xor(mx[r], m, 64));
  float sum[4] = {0.f, 0.f, 0.f, 0.f};
#pragma unroll
  for (int nt = 0; nt < 12; ++nt)
#pragma unroll
    for (int r = 0; r < 4; ++r) {
      float p = (sc[nt][r] > -1e37f) ? __expf(sc[nt][r] - mx[r]) : 0.f;
      sc[nt][r] = p;
      sum[r] += p;
    }
#pragma unroll
  for (int r = 0; r < 4; ++r)
#pragma unroll
    for (int m = 1; m <= 8; m <<= 1) sum[r] += __shfl_xor(sum[r], m, 64);
  float inv[4];
#pragma unroll
  for (int r = 0; r < 4; ++r) inv[r] = 1.f / sum[r];

  __syncthreads();

#pragma unroll
  for (int nt = 0; nt < 12; ++nt)
#pragma unroll
    for (int r = 0; r < 4; ++r)
      Ps[(w * 16 + qd * 4 + r) * 200 + nt * 16 + rm] = (bf16)(sc[nt][r] * inv[r]);

  f32x4 o[4] = {};
#pragma unroll
  for (int ks = 0; ks < 6; ++ks) {
    bf16x8 ap = *(const bf16x8*)&Ps[(w * 16 + rm) * 200 + ks * 32 + qd * 8];
#pragma unroll
    for (int nt = 0; nt < 4; ++nt) {
      int kc = ks * 4 + qd;
      bf16x8 bv = *(const bf16x8*)&Vts[(nt * 16 + rm) * 192 +
                                       (((kc & 24) | ((kc & 7) ^ (rm & 7))) * 8)];
      o[nt] = MFMA16(ap, bv, o[nt]);
    }
  }
#pragma unroll
  for (int nt = 0; nt < 4; ++nt)
#pragma unroll
    for (int r = 0; r < 4; ++r) {
      int q_ = s0 + w * 16 + qd * 4 + r;
      ctx[((size_t)(b * 2048 + q_)) * 768 + h * 64 + nt * 16 + rm] = (bf16)o[nt][r];
    }
}

// ---------------------------------------------------------------------------
extern "C" void kernel_launch(void* const* d_in, const int* in_sizes, int n_in,
                              void* d_out, int out_size, void* d_ws, size_t ws_size,
                              hipStream_t stream) {
  (void)in_sizes; (void)n_in; (void)out_size; (void)ws_size;
  const float* hidden = (const float*)d_in[0];
  const float* amask = (const float*)d_in[1];
  const float* g1 = (const float*)d_in[2];
  const float* wqkv = (const float*)d_in[3];
  const float* woa = (const float*)d_in[4];
  const float* g2 = (const float*)d_in[5];
  const float* wi = (const float*)d_in[6];
  const float* wom = (const float*)d_in[7];
  float* out = (float*)d_out;

  char* p = (char*)d_ws;
  size_t o = 0;
  auto take = [&](size_t bytes) {
    char* r = p + o;
    o = (o + bytes + 255) & ~(size_t)255;
    return r;
  };
  bf16* wqkvT = (bf16*)take((size_t)2304 * 768 * 2);
  bf16* woaT = (bf16*)take((size_t)768 * 768 * 2);
  bf16* wiIT = (bf16*)take((size_t)2304 * 768 * 2);   // interleaved rows
  bf16* womT = (bf16*)take((size_t)768 * 1152 * 2);
  bf16* xn = (bf16*)take((size_t)8192 * 768 * 2);     // LN out (reused for LN2)
  bf16* Qb = (bf16*)take((size_t)98304 * 64 * 2);
  bf16* Kb = (bf16*)take((size_t)98304 * 64 * 2);
  bf16* Vt = (bf16*)take((size_t)98304 * 64 * 2);     // [bh*64+d][s]
  bf16* ctxb = (bf16*)take((size_t)8192 * 768 * 2);
  float* hbuf = (float*)take((size_t)8192 * 768 * 4);
  bf16* mlp = (bf16*)take((size_t)8192 * 1152 * 2);

  // weights -> bf16 transposed (one launch)
  wconv_all<<<4896, 256, 0, stream>>>(wqkv, woa, wi, wom, wqkvT, woaT, wiIT, womT);

  // attention half
  ln_kernel<<<8192, 256, 0, stream>>>(hidden, g1, xn);
  gemm_qkv<<<dim3(18, 64), 256, 0, stream>>>(xn, wqkvT, Qb, Kb, Vt);
  attn_kernel<<<dim3(32, 48), 256, 0, stream>>>(Qb, Kb, Vt, amask, ctxb);
  gemm_bt<64, true, float><<<dim3(6, 128), 256, 0, stream>>>(ctxb, woaT, hidden, hbuf,
                                                             8192, 768, 768);

  // MLP half
  ln_kernel<<<8192, 256, 0, stream>>>(hbuf, g2, xn);
  gemm_wi<<<dim3(18, 64), 256, 0, stream>>>(xn, wiIT, mlp);
  gemm_bt<64, true, float><<<dim3(6, 128), 256, 0, stream>>>(mlp, womT, hbuf, out,
                                                             8192, 768, 1152);
}

// Round 5
// 330.537 us; speedup vs baseline: 1.0367x; 1.0367x over previous
//
#include <hip/hip_runtime.h>
#include <cstdint>
#include <cstddef>

typedef __bf16 bf16;
typedef float f32x4 __attribute__((ext_vector_type(4)));
typedef __bf16 bf16x8 __attribute__((ext_vector_type(8)));
typedef __bf16 bf16x4 __attribute__((ext_vector_type(4)));

#define MFMA16(a, b, c) __builtin_amdgcn_mfma_f32_16x16x32_bf16((a), (b), (c), 0, 0, 0)

__device__ __forceinline__ void gload_lds16(const void* g, void* l) {
  __builtin_amdgcn_global_load_lds((__attribute__((address_space(1))) void*)g,
                                   (__attribute__((address_space(3))) void*)l,
                                   16, 0, 0);
}

// ---------------------------------------------------------------------------
// All four weight transposes in one launch (flat grid). Plain [N][K] layout.
// ---------------------------------------------------------------------------
__global__ __launch_bounds__(256) void wconv_all(const float* __restrict__ wqkv,
                                                 const float* __restrict__ woa,
                                                 const float* __restrict__ wi,
                                                 const float* __restrict__ wom,
                                                 bf16* __restrict__ wqkvT,
                                                 bf16* __restrict__ woaT,
                                                 bf16* __restrict__ wiT,
                                                 bf16* __restrict__ womT) {
  int id = blockIdx.x;
  const float* W;
  bf16* Wt;
  int K, N, bx, by;
  if (id < 1728) { W = wqkv; Wt = wqkvT; K = 768; N = 2304; bx = id % 72; by = id / 72; }
  else if (id < 2304) { id -= 1728; W = woa; Wt = woaT; K = 768; N = 768; bx = id % 24; by = id / 24; }
  else if (id < 4032) { id -= 2304; W = wi; Wt = wiT; K = 768; N = 2304; bx = id % 72; by = id / 72; }
  else { id -= 4032; W = wom; Wt = womT; K = 1152; N = 768; bx = id % 24; by = id / 24; }

  __shared__ float tile[32][33];
  const int n0 = bx * 32, k0 = by * 32;
  const int t = threadIdx.x;
  const int c = t & 31, r = t >> 5;
#pragma unroll
  for (int i = 0; i < 4; ++i)
    tile[r + i * 8][c] = W[(size_t)(k0 + r + i * 8) * N + n0 + c];
  __syncthreads();
#pragma unroll
  for (int i = 0; i < 4; ++i)
    Wt[(size_t)(n0 + r + i * 8) * K + k0 + c] = (bf16)tile[c][r + i * 8];
}

// ---------------------------------------------------------------------------
// LayerNorm (center=False): subtract mean, no beta -> bf16
// ---------------------------------------------------------------------------
__global__ __launch_bounds__(256) void ln_kernel(const float* __restrict__ X,
                                                 const float* __restrict__ gamma,
                                                 bf16* __restrict__ out) {
  const int row = blockIdx.x, t = threadIdx.x;
  const float* xr = X + (size_t)row * 768;
  float v0 = xr[t], v1 = xr[t + 256], v2 = xr[t + 512];
  float s = v0 + v1 + v2;
  float s2 = v0 * v0 + v1 * v1 + v2 * v2;
#pragma unroll
  for (int m = 1; m <= 32; m <<= 1) {
    s += __shfl_xor(s, m, 64);
    s2 += __shfl_xor(s2, m, 64);
  }
  __shared__ float red[8];
  const int w = t >> 6, lane = t & 63;
  if (lane == 0) { red[w] = s; red[4 + w] = s2; }
  __syncthreads();
  s = red[0] + red[1] + red[2] + red[3];
  s2 = red[4] + red[5] + red[6] + red[7];
  const float mu = s * (1.f / 768.f);
  const float var = s2 * (1.f / 768.f) - mu * mu;
  const float rs = rsqrtf(var + 1e-5f);
  out[(size_t)row * 768 + t] = (bf16)((v0 - mu) * rs * gamma[t]);
  out[(size_t)row * 768 + t + 256] = (bf16)((v1 - mu) * rs * gamma[t + 256]);
  out[(size_t)row * 768 + t + 512] = (bf16)((v2 - mu) * rs * gamma[t + 512]);
}

// ---------------------------------------------------------------------------
// Generic NT GEMM: C[M][N] = A * Bt^T (+ f32 residual), TOUT out.
// GRID: x = row tile, y = col tile (consecutive blocks share the B tile -> L2).
// ---------------------------------------------------------------------------
template <int BM, bool RES, typename TOUT>
__global__ __launch_bounds__(256) void gemm_bt(const bf16* __restrict__ A,
                                               const bf16* __restrict__ Bt,
                                               const float* __restrict__ Res,
                                               TOUT* __restrict__ C, int M, int N, int K) {
  constexpr int MT = BM / 32;
  __shared__ __align__(16) bf16 As[BM * 64];
  __shared__ __align__(16) bf16 Bs[128 * 64];
  const int t = threadIdx.x;
  const int lane = t & 63;
  const int w = t >> 6;
  const int wm = w >> 1, wn = w & 1;
  const int row0 = blockIdx.x * BM, col0 = blockIdx.y * 128;
  const int rm = lane & 15, qd = lane >> 4;
  f32x4 acc[MT][4] = {};
  for (int k0 = 0; k0 < K; k0 += 64) {
#pragma unroll
    for (int i = 0; i < BM / 32; ++i) {
      int c = i * 256 + t;
      int r = c >> 3, j = (c & 7) ^ (r & 7);
      gload_lds16(A + (size_t)(row0 + r) * K + (k0 + j * 8), &As[c * 8]);
    }
#pragma unroll
    for (int i = 0; i < 4; ++i) {
      int c = i * 256 + t;
      int r = c >> 3, j = (c & 7) ^ (r & 7);
      gload_lds16(Bt + (size_t)(col0 + r) * K + (k0 + j * 8), &Bs[c * 8]);
    }
    __syncthreads();
#pragma unroll
    for (int kb = 0; kb < 2; ++kb) {
      bf16x8 af[MT], bfr[4];
#pragma unroll
      for (int mt = 0; mt < MT; ++mt) {
        int r = wm * (MT * 16) + mt * 16 + rm;
        af[mt] = *(const bf16x8*)&As[r * 64 + (((kb * 4 + qd) ^ (r & 7)) * 8)];
      }
#pragma unroll
      for (int nt = 0; nt < 4; ++nt) {
        int r = wn * 64 + nt * 16 + rm;
        bfr[nt] = *(const bf16x8*)&Bs[r * 64 + (((kb * 4 + qd) ^ (r & 7)) * 8)];
      }
#pragma unroll
      for (int mt = 0; mt < MT; ++mt)
#pragma unroll
        for (int nt = 0; nt < 4; ++nt)
          acc[mt][nt] = MFMA16(af[mt], bfr[nt], acc[mt][nt]);
    }
    __syncthreads();
  }
#pragma unroll
  for (int mt = 0; mt < MT; ++mt)
#pragma unroll
    for (int nt = 0; nt < 4; ++nt) {
      const int gc = col0 + wn * 64 + nt * 16 + rm;
#pragma unroll
      for (int r = 0; r < 4; ++r) {
        const int gr = row0 + wm * (MT * 16) + mt * 16 + qd * 4 + r;
        float v = acc[mt][nt][r];
        const size_t idx = (size_t)gr * N + gc;
        if (RES) v += Res[idx];
        C[idx] = (TOUT)v;
      }
    }
}

// ---------------------------------------------------------------------------
// QKV GEMM with fused RoPE + head-split + V-transpose epilogue.
// GRID: x = row tile (64), y = col tile (18). Col blocks type-homogeneous:
// by 0-5 -> Q heads, 6-11 -> K heads, 12-17 -> V heads.
// ---------------------------------------------------------------------------
__global__ __launch_bounds__(256) void gemm_qkv(const bf16* __restrict__ A,
                                                const bf16* __restrict__ Bt,
                                                bf16* __restrict__ Qb,
                                                bf16* __restrict__ Kb,
                                                bf16* __restrict__ Vt) {
  __shared__ __align__(16) bf16 SM[17408];  // As[8192] | Bs[8192]; scratch[128*136]
  bf16* As = SM;
  bf16* Bs = SM + 8192;

  const int t = threadIdx.x;
  const int lane = t & 63;
  const int w = t >> 6;
  const int wm = w >> 1, wn = w & 1;
  const int row0 = blockIdx.x * 128, col0 = blockIdx.y * 128;
  const int rm = lane & 15, qd = lane >> 4;
  f32x4 acc[4][4] = {};
  for (int k0 = 0; k0 < 768; k0 += 64) {
#pragma unroll
    for (int i = 0; i < 4; ++i) {
      int c = i * 256 + t;
      int r = c >> 3, j = (c & 7) ^ (r & 7);
      gload_lds16(A + (size_t)(row0 + r) * 768 + (k0 + j * 8), &As[c * 8]);
      gload_lds16(Bt + (size_t)(col0 + r) * 768 + (k0 + j * 8), &Bs[c * 8]);
    }
    __syncthreads();
#pragma unroll
    for (int kb = 0; kb < 2; ++kb) {
      bf16x8 af[4], bfr[4];
#pragma unroll
      for (int mt = 0; mt < 4; ++mt) {
        int r = wm * 64 + mt * 16 + rm;
        af[mt] = *(const bf16x8*)&As[r * 64 + (((kb * 4 + qd) ^ (r & 7)) * 8)];
      }
#pragma unroll
      for (int nt = 0; nt < 4; ++nt) {
        int r = wn * 64 + nt * 16 + rm;
        bfr[nt] = *(const bf16x8*)&Bs[r * 64 + (((kb * 4 + qd) ^ (r & 7)) * 8)];
      }
#pragma unroll
      for (int mt = 0; mt < 4; ++mt)
#pragma unroll
        for (int nt = 0; nt < 4; ++nt)
          acc[mt][nt] = MFMA16(af[mt], bfr[nt], acc[mt][nt]);
    }
    __syncthreads();
  }

  // ---- fused epilogue
  const int head_id = blockIdx.y * 2 + wn;  // 0..35
  const int typ = blockIdx.y / 6;           // block-uniform: 0=q 1=k 2=v
  const int b = row0 >> 11;
  const int sblk = row0 & 2047;
  const int sw = sblk + wm * 64;            // wave s-base

  if (typ < 2) {
    const int h = head_id - typ * 12;
    const size_t bhbase = (size_t)(b * 12 + h) * 2048;
    bf16* dst = typ ? Kb : Qb;
    float invf[2];
#pragma unroll
    for (int nt = 0; nt < 2; ++nt)
      invf[nt] = exp2f((float)(nt * 16 + rm) * -0.41524101186092029f);  // 10000^(-d/32)
#pragma unroll
    for (int mt = 0; mt < 4; ++mt)
#pragma unroll
      for (int r = 0; r < 4; ++r) {
        int s = sw + mt * 16 + qd * 4 + r;
#pragma unroll
        for (int nt = 0; nt < 2; ++nt) {
          float ang = (float)s * invf[nt];
          float rev = ang * 0.15915494309189535f;
          rev -= floorf(rev);
          float sn = __builtin_amdgcn_sinf(rev);
          float cs = __builtin_amdgcn_cosf(rev);
          float x1 = acc[mt][nt][r], x2 = acc[mt][nt + 2][r];
          int d = nt * 16 + rm;
          dst[(bhbase + s) * 64 + d] = (bf16)(x1 * cs - x2 * sn);
          dst[(bhbase + s) * 64 + d + 32] = (bf16)(x2 * cs + x1 * sn);
        }
      }
  } else {
    // write acc to scratch [hd][s], hd = wn*64 + d (128 rows, stride 136)
#pragma unroll
    for (int mt = 0; mt < 4; ++mt)
#pragma unroll
      for (int nt = 0; nt < 4; ++nt) {
        int hd = wn * 64 + nt * 16 + rm;
        int sl = wm * 64 + mt * 16 + qd * 4;  // 4 consecutive s
        bf16x4 v4;
#pragma unroll
        for (int r = 0; r < 4; ++r) v4[r] = (bf16)acc[mt][nt][r];
        *(bf16x4*)&SM[hd * 136 + sl] = v4;
      }
    __syncthreads();
    // coalesced read+store: 8 iters x 256 threads x 16B covers 128hd x 128s
    const int h0 = blockIdx.y * 2 - 24;  // first v-head of this block
#pragma unroll
    for (int it = 0; it < 8; ++it) {
      int cc = it * 256 + t;
      int hd = cc >> 4, s8 = (cc & 15) * 8;
      bf16x8 vv = *(const bf16x8*)&SM[hd * 136 + s8];
      size_t grow = (size_t)(b * 12 + h0 + (hd >> 6)) * 64 + (hd & 63);
      *(bf16x8*)&Vt[grow * 2048 + sblk + s8] = vv;
    }
  }
}

// ---------------------------------------------------------------------------
// Sliding-window attention (unchanged).
// ---------------------------------------------------------------------------
__global__ __launch_bounds__(256) void attn_kernel(const bf16* __restrict__ Qb,
                                                   const bf16* __restrict__ Kb,
                                                   const bf16* __restrict__ Vt,
                                                   const float* __restrict__ am,
                                                   bf16* __restrict__ ctx) {
  __shared__ __align__(16) bf16 KP[64 * 200];
  __shared__ __align__(16) bf16 Vts[64 * 192];
  bf16* Ks = KP;
  bf16* Ps = KP;

  const int t = threadIdx.x;
  const int lane = t & 63, w = t >> 6;
  const int rm = lane & 15, qd = lane >> 4;
  const int s0 = blockIdx.x * 64;
  const int bh = blockIdx.y;
  const int b = bh / 12, h = bh - b * 12;
  const size_t baseQ = (size_t)bh * 2048;

#pragma unroll
  for (int i = 0; i < 6; ++i) {
    int c = i * 256 + t;
    int r = c >> 3, j = (c & 7) ^ (r & 7);
    int key = min(max(s0 - 64 + r, 0), 2047);
    gload_lds16(Kb + (baseQ + key) * 64 + j * 8, &Ks[c * 8]);
  }
#pragma unroll
  for (int i = 0; i < 6; ++i) {
    int c = i * 256 + t;
    int r = c / 24, jl = c - r * 24;
    int j = (jl & 24) | ((jl & 7) ^ (r & 7));
    int k0 = min(max(s0 - 64 + j * 8, 0), 2040);
    gload_lds16(Vt + ((size_t)bh * 64 + r) * 2048 + k0, &Vts[c * 8]);
  }

  bf16x8 aq[2];
#pragma unroll
  for (int kb = 0; kb < 2; ++kb)
    aq[kb] = *(const bf16x8*)&Qb[(baseQ + s0 + w * 16 + rm) * 64 + kb * 32 + qd * 8];

  float msk[12][4];
#pragma unroll
  for (int nt = 0; nt < 12; ++nt) {
    int key = s0 - 64 + nt * 16 + rm;
#pragma unroll
    for (int r = 0; r < 4; ++r) {
      int qpos = s0 + w * 16 + qd * 4 + r;
      bool valid = (key >= 0) && (key < 2048) && (key - qpos <= 64) && (qpos - key <= 64);
      msk[nt][r] = valid ? am[((size_t)b * 2048 + qpos) * 2048 + key] : -3e38f;
    }
  }
  __syncthreads();

  f32x4 sc[12];
#pragma unroll
  for (int nt = 0; nt < 12; ++nt) {
    f32x4 a = {0.f, 0.f, 0.f, 0.f};
#pragma unroll
    for (int kb = 0; kb < 2; ++kb) {
      int r = nt * 16 + rm;
      bf16x8 bk = *(const bf16x8*)&Ks[r * 64 + (((kb * 4 + qd) ^ (rm & 7)) * 8)];
      a = MFMA16(aq[kb], bk, a);
    }
    sc[nt] = a;
  }

  float mx[4] = {-3e38f, -3e38f, -3e38f, -3e38f};
#pragma unroll
  for (int nt = 0; nt < 12; ++nt)
#pragma unroll
    for (int r = 0; r < 4; ++r) {
      float v = (msk[nt][r] <= -2.9e38f) ? -3e38f : sc[nt][r] * 0.125f + msk[nt][r];
      sc[nt][r] = v;
      mx[r] = fmaxf(mx[r], v);
    }
#pragma unroll
  for (int r = 0; r < 4; ++r)
#pragma unroll
    for (int m = 1; m <= 8; m <<= 1) mx[r] = fmaxf(mx[r], __shfl_xor(mx[r], m, 64));
  float sum[4] = {0.f, 0.f, 0.f, 0.f};
#pragma unroll
  for (int nt = 0; nt < 12; ++nt)
#pragma unroll
    for (int r = 0; r < 4; ++r) {
      float p = (sc[nt][r] > -1e37f) ? __expf(sc[nt][r] - mx[r]) : 0.f;
      sc[nt][r] = p;
      sum[r] += p;
    }
#pragma unroll
  for (int r = 0; r < 4; ++r)
#pragma unroll
    for (int m = 1; m <= 8; m <<= 1) sum[r] += __shfl_xor(sum[r], m, 64);
  float inv[4];
#pragma unroll
  for (int r = 0; r < 4; ++r) inv[r] = 1.f / sum[r];

  __syncthreads();

#pragma unroll
  for (int nt = 0; nt < 12; ++nt)
#pragma unroll
    for (int r = 0; r < 4; ++r)
      Ps[(w * 16 + qd * 4 + r) * 200 + nt * 16 + rm] = (bf16)(sc[nt][r] * inv[r]);

  f32x4 o[4] = {};
#pragma unroll
  for (int ks = 0; ks < 6; ++ks) {
    bf16x8 ap = *(const bf16x8*)&Ps[(w * 16 + rm) * 200 + ks * 32 + qd * 8];
#pragma unroll
    for (int nt = 0; nt < 4; ++nt) {
      int kc = ks * 4 + qd;
      bf16x8 bv = *(const bf16x8*)&Vts[(nt * 16 + rm) * 192 +
                                       (((kc & 24) | ((kc & 7) ^ (rm & 7))) * 8)];
      o[nt] = MFMA16(ap, bv, o[nt]);
    }
  }
#pragma unroll
  for (int nt = 0; nt < 4; ++nt)
#pragma unroll
    for (int r = 0; r < 4; ++r) {
      int q_ = s0 + w * 16 + qd * 4 + r;
      ctx[((size_t)(b * 2048 + q_)) * 768 + h * 64 + nt * 16 + rm] = (bf16)o[nt][r];
    }
}

// ---------------------------------------------------------------------------
// GeGLU: out = gelu(X[:, :1152]) * X[:, 1152:]  (bf16 in/out)
// ---------------------------------------------------------------------------
__global__ __launch_bounds__(128) void geglu_kernel(const bf16* __restrict__ X,
                                                    bf16* __restrict__ out) {
  const int row = blockIdx.y;
  const int c = blockIdx.x * 128 + threadIdx.x;
  const bf16* xr = X + (size_t)row * 2304;
  float x = (float)xr[c], g = (float)xr[1152 + c];
  float ge = 0.5f * x * (1.0f + erff(x * 0.70710678118654752f));
  out[(size_t)row * 1152 + c] = (bf16)(ge * g);
}

// ---------------------------------------------------------------------------
extern "C" void kernel_launch(void* const* d_in, const int* in_sizes, int n_in,
                              void* d_out, int out_size, void* d_ws, size_t ws_size,
                              hipStream_t stream) {
  (void)in_sizes; (void)n_in; (void)out_size; (void)ws_size;
  const float* hidden = (const float*)d_in[0];
  const float* amask = (const float*)d_in[1];
  const float* g1 = (const float*)d_in[2];
  const float* wqkv = (const float*)d_in[3];
  const float* woa = (const float*)d_in[4];
  const float* g2 = (const float*)d_in[5];
  const float* wi = (const float*)d_in[6];
  const float* wom = (const float*)d_in[7];
  float* out = (float*)d_out;

  char* p = (char*)d_ws;
  size_t o = 0;
  auto take = [&](size_t bytes) {
    char* r = p + o;
    o = (o + bytes + 255) & ~(size_t)255;
    return r;
  };
  bf16* wqkvT = (bf16*)take((size_t)2304 * 768 * 2);
  bf16* woaT = (bf16*)take((size_t)768 * 768 * 2);
  bf16* wiT = (bf16*)take((size_t)2304 * 768 * 2);
  bf16* womT = (bf16*)take((size_t)768 * 1152 * 2);
  bf16* xn = (bf16*)take((size_t)8192 * 768 * 2);     // LN out (reused for LN2)
  bf16* Qb = (bf16*)take((size_t)98304 * 64 * 2);
  bf16* Kb = (bf16*)take((size_t)98304 * 64 * 2);
  bf16* Vt = (bf16*)take((size_t)98304 * 64 * 2);     // [bh*64+d][s]
  bf16* ctxb = (bf16*)take((size_t)8192 * 768 * 2);
  float* hbuf = (float*)take((size_t)8192 * 768 * 4);
  bf16* mlpx = (bf16*)take((size_t)8192 * 2304 * 2);  // Wi out (x | gate)
  bf16* mlp = (bf16*)take((size_t)8192 * 1152 * 2);

  // weights -> bf16 transposed (one launch)
  wconv_all<<<4896, 256, 0, stream>>>(wqkv, woa, wi, wom, wqkvT, woaT, wiT, womT);

  // attention half
  ln_kernel<<<8192, 256, 0, stream>>>(hidden, g1, xn);
  gemm_qkv<<<dim3(64, 18), 256, 0, stream>>>(xn, wqkvT, Qb, Kb, Vt);
  attn_kernel<<<dim3(32, 48), 256, 0, stream>>>(Qb, Kb, Vt, amask, ctxb);
  gemm_bt<64, true, float><<<dim3(128, 6), 256, 0, stream>>>(ctxb, woaT, hidden, hbuf,
                                                             8192, 768, 768);

  // MLP half
  ln_kernel<<<8192, 256, 0, stream>>>(hbuf, g2, xn);
  gemm_bt<128, false, bf16><<<dim3(64, 18), 256, 0, stream>>>(xn, wiT, nullptr, mlpx,
                                                              8192, 2304, 768);
  geglu_kernel<<<dim3(9, 8192), 128, 0, stream>>>(mlpx, mlp);
  gemm_bt<64, true, float><<<dim3(128, 6), 256, 0, stream>>>(mlp, womT, hbuf, out,
                                                             8192, 768, 1152);
}

// Round 6
// 325.795 us; speedup vs baseline: 1.0517x; 1.0146x over previous
//
#include <hip/hip_runtime.h>
#include <cstdint>
#include <cstddef>

typedef __bf16 bf16;
typedef float f32x4 __attribute__((ext_vector_type(4)));
typedef __bf16 bf16x8 __attribute__((ext_vector_type(8)));
typedef __bf16 bf16x4 __attribute__((ext_vector_type(4)));
typedef __bf16 bf16x2 __attribute__((ext_vector_type(2)));

#define MFMA16(a, b, c) __builtin_amdgcn_mfma_f32_16x16x32_bf16((a), (b), (c), 0, 0, 0)

__device__ __forceinline__ void gload_lds16(const void* g, void* l) {
  __builtin_amdgcn_global_load_lds((__attribute__((address_space(1))) void*)g,
                                   (__attribute__((address_space(3))) void*)l,
                                   16, 0, 0);
}

// ---------------------------------------------------------------------------
// Fused: four weight transposes (blocks 0..4895) + LayerNorm1 (blocks 4896..)
// ---------------------------------------------------------------------------
__global__ __launch_bounds__(256) void wconv_ln(const float* __restrict__ wqkv,
                                                const float* __restrict__ woa,
                                                const float* __restrict__ wi,
                                                const float* __restrict__ wom,
                                                bf16* __restrict__ wqkvT,
                                                bf16* __restrict__ woaT,
                                                bf16* __restrict__ wiT,
                                                bf16* __restrict__ womT,
                                                const float* __restrict__ X,
                                                const float* __restrict__ gamma,
                                                bf16* __restrict__ xnout) {
  __shared__ float tile[32][33];
  const int t = threadIdx.x;
  int id = blockIdx.x;
  if (id >= 4896) {
    // ---- LayerNorm (center=False)
    const int row = id - 4896;
    const float* xr = X + (size_t)row * 768;
    float v0 = xr[t], v1 = xr[t + 256], v2 = xr[t + 512];
    float s = v0 + v1 + v2;
    float s2 = v0 * v0 + v1 * v1 + v2 * v2;
#pragma unroll
    for (int m = 1; m <= 32; m <<= 1) {
      s += __shfl_xor(s, m, 64);
      s2 += __shfl_xor(s2, m, 64);
    }
    float* red = &tile[0][0];
    const int w = t >> 6, lane = t & 63;
    if (lane == 0) { red[w] = s; red[4 + w] = s2; }
    __syncthreads();
    s = red[0] + red[1] + red[2] + red[3];
    s2 = red[4] + red[5] + red[6] + red[7];
    const float mu = s * (1.f / 768.f);
    const float var = s2 * (1.f / 768.f) - mu * mu;
    const float rs = rsqrtf(var + 1e-5f);
    xnout[(size_t)row * 768 + t] = (bf16)((v0 - mu) * rs * gamma[t]);
    xnout[(size_t)row * 768 + t + 256] = (bf16)((v1 - mu) * rs * gamma[t + 256]);
    xnout[(size_t)row * 768 + t + 512] = (bf16)((v2 - mu) * rs * gamma[t + 512]);
    return;
  }
  // ---- weight transpose f32->bf16
  const float* W;
  bf16* Wt;
  int K, N, bx, by;
  if (id < 1728) { W = wqkv; Wt = wqkvT; K = 768; N = 2304; bx = id % 72; by = id / 72; }
  else if (id < 2304) { id -= 1728; W = woa; Wt = woaT; K = 768; N = 768; bx = id % 24; by = id / 24; }
  else if (id < 4032) { id -= 2304; W = wi; Wt = wiT; K = 768; N = 2304; bx = id % 72; by = id / 72; }
  else { id -= 4032; W = wom; Wt = womT; K = 1152; N = 768; bx = id % 24; by = id / 24; }
  const int n0 = bx * 32, k0 = by * 32;
  const int c = t & 31, r = t >> 5;
#pragma unroll
  for (int i = 0; i < 4; ++i)
    tile[r + i * 8][c] = W[(size_t)(k0 + r + i * 8) * N + n0 + c];
  __syncthreads();
#pragma unroll
  for (int i = 0; i < 4; ++i)
    Wt[(size_t)(n0 + r + i * 8) * K + k0 + c] = (bf16)tile[c][r + i * 8];
}

// ---------------------------------------------------------------------------
// LayerNorm (center=False) standalone (for ln2)
// ---------------------------------------------------------------------------
__global__ __launch_bounds__(256) void ln_kernel(const float* __restrict__ X,
                                                 const float* __restrict__ gamma,
                                                 bf16* __restrict__ out) {
  const int row = blockIdx.x, t = threadIdx.x;
  const float* xr = X + (size_t)row * 768;
  float v0 = xr[t], v1 = xr[t + 256], v2 = xr[t + 512];
  float s = v0 + v1 + v2;
  float s2 = v0 * v0 + v1 * v1 + v2 * v2;
#pragma unroll
  for (int m = 1; m <= 32; m <<= 1) {
    s += __shfl_xor(s, m, 64);
    s2 += __shfl_xor(s2, m, 64);
  }
  __shared__ float red[8];
  const int w = t >> 6, lane = t & 63;
  if (lane == 0) { red[w] = s; red[4 + w] = s2; }
  __syncthreads();
  s = red[0] + red[1] + red[2] + red[3];
  s2 = red[4] + red[5] + red[6] + red[7];
  const float mu = s * (1.f / 768.f);
  const float var = s2 * (1.f / 768.f) - mu * mu;
  const float rs = rsqrtf(var + 1e-5f);
  out[(size_t)row * 768 + t] = (bf16)((v0 - mu) * rs * gamma[t]);
  out[(size_t)row * 768 + t + 256] = (bf16)((v1 - mu) * rs * gamma[t + 256]);
  out[(size_t)row * 768 + t + 512] = (bf16)((v2 - mu) * rs * gamma[t + 512]);
}

// ---------------------------------------------------------------------------
// Generic NT GEMM: C[M][N] = A * Bt^T (+ f32 residual), TOUT out.
// GRID: x = row tile, y = col tile (consecutive blocks share the B tile -> L2).
// ---------------------------------------------------------------------------
template <int BM, bool RES, typename TOUT>
__global__ __launch_bounds__(256) void gemm_bt(const bf16* __restrict__ A,
                                               const bf16* __restrict__ Bt,
                                               const float* __restrict__ Res,
                                               TOUT* __restrict__ C, int M, int N, int K) {
  constexpr int MT = BM / 32;
  __shared__ __align__(16) bf16 As[BM * 64];
  __shared__ __align__(16) bf16 Bs[128 * 64];
  const int t = threadIdx.x;
  const int lane = t & 63;
  const int w = t >> 6;
  const int wm = w >> 1, wn = w & 1;
  const int row0 = blockIdx.x * BM, col0 = blockIdx.y * 128;
  const int rm = lane & 15, qd = lane >> 4;
  f32x4 acc[MT][4] = {};
  for (int k0 = 0; k0 < K; k0 += 64) {
#pragma unroll
    for (int i = 0; i < BM / 32; ++i) {
      int c = i * 256 + t;
      int r = c >> 3, j = (c & 7) ^ (r & 7);
      gload_lds16(A + (size_t)(row0 + r) * K + (k0 + j * 8), &As[c * 8]);
    }
#pragma unroll
    for (int i = 0; i < 4; ++i) {
      int c = i * 256 + t;
      int r = c >> 3, j = (c & 7) ^ (r & 7);
      gload_lds16(Bt + (size_t)(col0 + r) * K + (k0 + j * 8), &Bs[c * 8]);
    }
    __syncthreads();
#pragma unroll
    for (int kb = 0; kb < 2; ++kb) {
      bf16x8 af[MT], bfr[4];
#pragma unroll
      for (int mt = 0; mt < MT; ++mt) {
        int r = wm * (MT * 16) + mt * 16 + rm;
        af[mt] = *(const bf16x8*)&As[r * 64 + (((kb * 4 + qd) ^ (r & 7)) * 8)];
      }
#pragma unroll
      for (int nt = 0; nt < 4; ++nt) {
        int r = wn * 64 + nt * 16 + rm;
        bfr[nt] = *(const bf16x8*)&Bs[r * 64 + (((kb * 4 + qd) ^ (r & 7)) * 8)];
      }
#pragma unroll
      for (int mt = 0; mt < MT; ++mt)
#pragma unroll
        for (int nt = 0; nt < 4; ++nt)
          acc[mt][nt] = MFMA16(af[mt], bfr[nt], acc[mt][nt]);
    }
    __syncthreads();
  }
#pragma unroll
  for (int mt = 0; mt < MT; ++mt)
#pragma unroll
    for (int nt = 0; nt < 4; ++nt) {
      const int gc = col0 + wn * 64 + nt * 16 + rm;
#pragma unroll
      for (int r = 0; r < 4; ++r) {
        const int gr = row0 + wm * (MT * 16) + mt * 16 + qd * 4 + r;
        float v = acc[mt][nt][r];
        const size_t idx = (size_t)gr * N + gc;
        if (RES) v += Res[idx];
        C[idx] = (TOUT)v;
      }
    }
}

// ---------------------------------------------------------------------------
// QKV GEMM + fused RoPE/head-split/V-transpose.
// RoPE pairs (d, d+32) stored PERMUTED at (2d, 2d+1) -> one 4B store per pair.
// QK^T is invariant to the shared d-permutation of Q and K.
// Trig via rotation recurrence: 6 sincos + 15 rotations per freq.
// GRID: x = row tile (64), y = col tile (18); by 0-5 Q, 6-11 K, 12-17 V.
// ---------------------------------------------------------------------------
__global__ __launch_bounds__(256) void gemm_qkv(const bf16* __restrict__ A,
                                                const bf16* __restrict__ Bt,
                                                bf16* __restrict__ Qb,
                                                bf16* __restrict__ Kb,
                                                bf16* __restrict__ Vt) {
  __shared__ __align__(16) bf16 SM[17408];  // As[8192] | Bs[8192]; scratch[128*136]
  bf16* As = SM;
  bf16* Bs = SM + 8192;

  const int t = threadIdx.x;
  const int lane = t & 63;
  const int w = t >> 6;
  const int wm = w >> 1, wn = w & 1;
  const int row0 = blockIdx.x * 128, col0 = blockIdx.y * 128;
  const int rm = lane & 15, qd = lane >> 4;
  f32x4 acc[4][4] = {};
  for (int k0 = 0; k0 < 768; k0 += 64) {
#pragma unroll
    for (int i = 0; i < 4; ++i) {
      int c = i * 256 + t;
      int r = c >> 3, j = (c & 7) ^ (r & 7);
      gload_lds16(A + (size_t)(row0 + r) * 768 + (k0 + j * 8), &As[c * 8]);
      gload_lds16(Bt + (size_t)(col0 + r) * 768 + (k0 + j * 8), &Bs[c * 8]);
    }
    __syncthreads();
#pragma unroll
    for (int kb = 0; kb < 2; ++kb) {
      bf16x8 af[4], bfr[4];
#pragma unroll
      for (int mt = 0; mt < 4; ++mt) {
        int r = wm * 64 + mt * 16 + rm;
        af[mt] = *(const bf16x8*)&As[r * 64 + (((kb * 4 + qd) ^ (r & 7)) * 8)];
      }
#pragma unroll
      for (int nt = 0; nt < 4; ++nt) {
        int r = wn * 64 + nt * 16 + rm;
        bfr[nt] = *(const bf16x8*)&Bs[r * 64 + (((kb * 4 + qd) ^ (r & 7)) * 8)];
      }
#pragma unroll
      for (int mt = 0; mt < 4; ++mt)
#pragma unroll
        for (int nt = 0; nt < 4; ++nt)
          acc[mt][nt] = MFMA16(af[mt], bfr[nt], acc[mt][nt]);
    }
    __syncthreads();
  }

  // ---- fused epilogue
  const int head_id = blockIdx.y * 2 + wn;  // 0..35
  const int typ = blockIdx.y / 6;           // block-uniform: 0=q 1=k 2=v
  const int b = row0 >> 11;
  const int sblk = row0 & 2047;
  const int sw = sblk + wm * 64;            // wave s-base

  if (typ < 2) {
    const int h = head_id - typ * 12;
    const size_t bhbase = (size_t)(b * 12 + h) * 2048;
    bf16* dst = typ ? Kb : Qb;
    constexpr float inv2pi = 0.15915494309189535f;
#pragma unroll
    for (int nt = 0; nt < 2; ++nt) {
      const int d = nt * 16 + rm;  // logical freq index 0..31
      const float invf = exp2f((float)d * -0.41524101186092029f);  // 10000^(-d/32)
      // initial angle at s_first = sw + qd*4
      float rev = (float)(sw + qd * 4) * invf * inv2pi;
      rev -= floorf(rev);
      float cs = __builtin_amdgcn_cosf(rev);
      float sn = __builtin_amdgcn_sinf(rev);
      // step angles: +1 (within r) and +13 (r=3 -> next mt r=0)
      float rv1 = invf * inv2pi;
      float c1 = __builtin_amdgcn_cosf(rv1), s1 = __builtin_amdgcn_sinf(rv1);
      float rv13 = 13.f * invf * inv2pi;
      rv13 -= floorf(rv13);
      float c13 = __builtin_amdgcn_cosf(rv13), s13 = __builtin_amdgcn_sinf(rv13);
#pragma unroll
      for (int mt = 0; mt < 4; ++mt)
#pragma unroll
        for (int r = 0; r < 4; ++r) {
          const int s = sw + mt * 16 + qd * 4 + r;
          const float x1 = acc[mt][nt][r], x2 = acc[mt][nt + 2][r];
          bf16x2 v2;
          v2[0] = (bf16)(x1 * cs - x2 * sn);
          v2[1] = (bf16)(x2 * cs + x1 * sn);
          *(bf16x2*)&dst[(bhbase + s) * 64 + 2 * d] = v2;
          const float ca = (r < 3) ? c1 : c13, sa = (r < 3) ? s1 : s13;
          const float cn = cs * ca - sn * sa;
          sn = sn * ca + cs * sa;
          cs = cn;
        }
    }
  } else {
    // write acc to scratch [hd][s], hd = wn*64 + d (128 rows, stride 136)
#pragma unroll
    for (int mt = 0; mt < 4; ++mt)
#pragma unroll
      for (int nt = 0; nt < 4; ++nt) {
        int hd = wn * 64 + nt * 16 + rm;
        int sl = wm * 64 + mt * 16 + qd * 4;  // 4 consecutive s
        bf16x4 v4;
#pragma unroll
        for (int r = 0; r < 4; ++r) v4[r] = (bf16)acc[mt][nt][r];
        *(bf16x4*)&SM[hd * 136 + sl] = v4;
      }
    __syncthreads();
    // coalesced read+store: 8 iters x 256 threads x 16B covers 128hd x 128s
    const int h0 = blockIdx.y * 2 - 24;  // first v-head of this block
#pragma unroll
    for (int it = 0; it < 8; ++it) {
      int cc = it * 256 + t;
      int hd = cc >> 4, s8 = (cc & 15) * 8;
      bf16x8 vv = *(const bf16x8*)&SM[hd * 136 + s8];
      size_t grow = (size_t)(b * 12 + h0 + (hd >> 6)) * 64 + (hd & 63);
      *(bf16x8*)&Vt[grow * 2048 + sblk + s8] = vv;
    }
  }
}

// ---------------------------------------------------------------------------
// Sliding-window attention (unchanged; Q/K d-permutation cancels in QK^T).
// ---------------------------------------------------------------------------
__global__ __launch_bounds__(256) void attn_kernel(const bf16* __restrict__ Qb,
                                                   const bf16* __restrict__ Kb,
                                                   const bf16* __restrict__ Vt,
                                                   const float* __restrict__ am,
                                                   bf16* __restrict__ ctx) {
  __shared__ __align__(16) bf16 KP[64 * 200];
  __shared__ __align__(16) bf16 Vts[64 * 192];
  bf16* Ks = KP;
  bf16* Ps = KP;

  const int t = threadIdx.x;
  const int lane = t & 63, w = t >> 6;
  const int rm = lane & 15, qd = lane >> 4;
  const int s0 = blockIdx.x * 64;
  const int bh = blockIdx.y;
  const int b = bh / 12, h = bh - b * 12;
  const size_t baseQ = (size_t)bh * 2048;

#pragma unroll
  for (int i = 0; i < 6; ++i) {
    int c = i * 256 + t;
    int r = c >> 3, j = (c & 7) ^ (r & 7);
    int key = min(max(s0 - 64 + r, 0), 2047);
    gload_lds16(Kb + (baseQ + key) * 64 + j * 8, &Ks[c * 8]);
  }
#pragma unroll
  for (int i = 0; i < 6; ++i) {
    int c = i * 256 + t;
    int r = c / 24, jl = c - r * 24;
    int j = (jl & 24) | ((jl & 7) ^ (r & 7));
    int k0 = min(max(s0 - 64 + j * 8, 0), 2040);
    gload_lds16(Vt + ((size_t)bh * 64 + r) * 2048 + k0, &Vts[c * 8]);
  }

  bf16x8 aq[2];
#pragma unroll
  for (int kb = 0; kb < 2; ++kb)
    aq[kb] = *(const bf16x8*)&Qb[(baseQ + s0 + w * 16 + rm) * 64 + kb * 32 + qd * 8];

  float msk[12][4];
#pragma unroll
  for (int nt = 0; nt < 12; ++nt) {
    int key = s0 - 64 + nt * 16 + rm;
#pragma unroll
    for (int r = 0; r < 4; ++r) {
      int qpos = s0 + w * 16 + qd * 4 + r;
      bool valid = (key >= 0) && (key < 2048) && (key - qpos <= 64) && (qpos - key <= 64);
      msk[nt][r] = valid ? am[((size_t)b * 2048 + qpos) * 2048 + key] : -3e38f;
    }
  }
  __syncthreads();

  f32x4 sc[12];
#pragma unroll
  for (int nt = 0; nt < 12; ++nt) {
    f32x4 a = {0.f, 0.f, 0.f, 0.f};
#pragma unroll
    for (int kb = 0; kb < 2; ++kb) {
      int r = nt * 16 + rm;
      bf16x8 bk = *(const bf16x8*)&Ks[r * 64 + (((kb * 4 + qd) ^ (rm & 7)) * 8)];
      a = MFMA16(aq[kb], bk, a);
    }
    sc[nt] = a;
  }

  float mx[4] = {-3e38f, -3e38f, -3e38f, -3e38f};
#pragma unroll
  for (int nt = 0; nt < 12; ++nt)
#pragma unroll
    for (int r = 0; r < 4; ++r) {
      float v = (msk[nt][r] <= -2.9e38f) ? -3e38f : sc[nt][r] * 0.125f + msk[nt][r];
      sc[nt][r] = v;
      mx[r] = fmaxf(mx[r], v);
    }
#pragma unroll
  for (int r = 0; r < 4; ++r)
#pragma unroll
    for (int m = 1; m <= 8; m <<= 1) mx[r] = fmaxf(mx[r], __shfl_xor(mx[r], m, 64));
  float sum[4] = {0.f, 0.f, 0.f, 0.f};
#pragma unroll
  for (int nt = 0; nt < 12; ++nt)
#pragma unroll
    for (int r = 0; r < 4; ++r) {
      float p = (sc[nt][r] > -1e37f) ? __expf(sc[nt][r] - mx[r]) : 0.f;
      sc[nt][r] = p;
      sum[r] += p;
    }
#pragma unroll
  for (int r = 0; r < 4; ++r)
#pragma unroll
    for (int m = 1; m <= 8; m <<= 1) sum[r] += __shfl_xor(sum[r], m, 64);
  float inv[4];
#pragma unroll
  for (int r = 0; r < 4; ++r) inv[r] = 1.f / sum[r];

  __syncthreads();

#pragma unroll
  for (int nt = 0; nt < 12; ++nt)
#pragma unroll
    for (int r = 0; r < 4; ++r)
      Ps[(w * 16 + qd * 4 + r) * 200 + nt * 16 + rm] = (bf16)(sc[nt][r] * inv[r]);

  f32x4 o[4] = {};
#pragma unroll
  for (int ks = 0; ks < 6; ++ks) {
    bf16x8 ap = *(const bf16x8*)&Ps[(w * 16 + rm) * 200 + ks * 32 + qd * 8];
#pragma unroll
    for (int nt = 0; nt < 4; ++nt) {
      int kc = ks * 4 + qd;
      bf16x8 bv = *(const bf16x8*)&Vts[(nt * 16 + rm) * 192 +
                                       (((kc & 24) | ((kc & 7) ^ (rm & 7))) * 8)];
      o[nt] = MFMA16(ap, bv, o[nt]);
    }
  }
#pragma unroll
  for (int nt = 0; nt < 4; ++nt)
#pragma unroll
    for (int r = 0; r < 4; ++r) {
      int q_ = s0 + w * 16 + qd * 4 + r;
      ctx[((size_t)(b * 2048 + q_)) * 768 + h * 64 + nt * 16 + rm] = (bf16)o[nt][r];
    }
}

// ---------------------------------------------------------------------------
// GeGLU: out = gelu(X[:, :1152]) * X[:, 1152:]  (bf16 in/out)
// ---------------------------------------------------------------------------
__global__ __launch_bounds__(128) void geglu_kernel(const bf16* __restrict__ X,
                                                    bf16* __restrict__ out) {
  const int row = blockIdx.y;
  const int c = blockIdx.x * 128 + threadIdx.x;
  const bf16* xr = X + (size_t)row * 2304;
  float x = (float)xr[c], g = (float)xr[1152 + c];
  float ge = 0.5f * x * (1.0f + erff(x * 0.70710678118654752f));
  out[(size_t)row * 1152 + c] = (bf16)(ge * g);
}

// ---------------------------------------------------------------------------
extern "C" void kernel_launch(void* const* d_in, const int* in_sizes, int n_in,
                              void* d_out, int out_size, void* d_ws, size_t ws_size,
                              hipStream_t stream) {
  (void)in_sizes; (void)n_in; (void)out_size; (void)ws_size;
  const float* hidden = (const float*)d_in[0];
  const float* amask = (const float*)d_in[1];
  const float* g1 = (const float*)d_in[2];
  const float* wqkv = (const float*)d_in[3];
  const float* woa = (const float*)d_in[4];
  const float* g2 = (const float*)d_in[5];
  const float* wi = (const float*)d_in[6];
  const float* wom = (const float*)d_in[7];
  float* out = (float*)d_out;

  char* p = (char*)d_ws;
  size_t o = 0;
  auto take = [&](size_t bytes) {
    char* r = p + o;
    o = (o + bytes + 255) & ~(size_t)255;
    return r;
  };
  bf16* wqkvT = (bf16*)take((size_t)2304 * 768 * 2);
  bf16* woaT = (bf16*)take((size_t)768 * 768 * 2);
  bf16* wiT = (bf16*)take((size_t)2304 * 768 * 2);
  bf16* womT = (bf16*)take((size_t)768 * 1152 * 2);
  bf16* xn = (bf16*)take((size_t)8192 * 768 * 2);     // LN out (reused for LN2)
  bf16* Qb = (bf16*)take((size_t)98304 * 64 * 2);     // d-permuted RoPE'd
  bf16* Kb = (bf16*)take((size_t)98304 * 64 * 2);     // d-permuted RoPE'd
  bf16* Vt = (bf16*)take((size_t)98304 * 64 * 2);     // [bh*64+d][s]
  bf16* ctxb = (bf16*)take((size_t)8192 * 768 * 2);
  float* hbuf = (float*)take((size_t)8192 * 768 * 4);
  bf16* mlpx = (bf16*)take((size_t)8192 * 2304 * 2);  // Wi out (x | gate)
  bf16* mlp = (bf16*)take((size_t)8192 * 1152 * 2);

  // weights -> bf16 transposed + LN1 (one launch)
  wconv_ln<<<13088, 256, 0, stream>>>(wqkv, woa, wi, wom, wqkvT, woaT, wiT, womT,
                                      hidden, g1, xn);

  // attention half
  gemm_qkv<<<dim3(64, 18), 256, 0, stream>>>(xn, wqkvT, Qb, Kb, Vt);
  attn_kernel<<<dim3(32, 48), 256, 0, stream>>>(Qb, Kb, Vt, amask, ctxb);
  gemm_bt<64, true, float><<<dim3(128, 6), 256, 0, stream>>>(ctxb, woaT, hidden, hbuf,
                                                             8192, 768, 768);

  // MLP half
  ln_kernel<<<8192, 256, 0, stream>>>(hbuf, g2, xn);
  gemm_bt<128, false, bf16><<<dim3(64, 18), 256, 0, stream>>>(xn, wiT, nullptr, mlpx,
                                                              8192, 2304, 768);
  geglu_kernel<<<dim3(9, 8192), 128, 0, stream>>>(mlpx, mlp);
  gemm_bt<64, true, float><<<dim3(128, 6), 256, 0, stream>>>(mlp, womT, hbuf, out,
                                                             8192, 768, 1152);
}